// Round 13
// baseline (631.163 us; speedup 1.0000x reference)
//
#include <hip/hip_runtime.h>

typedef float  f32x4  __attribute__((ext_vector_type(4)));
typedef __bf16 bf16x4 __attribute__((ext_vector_type(4)));
typedef __bf16 bf16x8 __attribute__((ext_vector_type(8)));

#define B_     16
#define N_     6000
#define D_     512
#define H_     6
#define DH_    64
#define INNER_ 384
#define M_     20
#define L_     300
#define KW_    33
#define ROWS_  (B_ * N_)     // 96000
#define SCALE_ 0.125f        // 64^-0.5
#define CH2_   128           // attn3 chunk rows (MFMA version)
#define NCH2_  47            // ceil(6000/128)

__device__ __forceinline__ ushort f2bf(float f) {
    __bf16 h = (__bf16)f;                    // v_cvt (RNE)
    return __builtin_bit_cast(ushort, h);
}
__device__ __forceinline__ float bf2f(ushort h) {
    return __uint_as_float(((unsigned)h) << 16);
}

// async global->LDS, 16B per lane; LDS dest = wave-uniform base + lane*16
#define GLD(gp, lp) __builtin_amdgcn_global_load_lds( \
    (const __attribute__((address_space(1))) unsigned int*)(gp), \
    (__attribute__((address_space(3))) unsigned int*)(lp), 16, 0, 0)

// ---------------- LayerNorm: wave-per-row, shfl-only, no LDS ----------------
__global__ __launch_bounds__(256) void ln_kernel(const float* __restrict__ x,
        const float* __restrict__ w, const float* __restrict__ b,
        ushort* __restrict__ xn) {
    int row  = blockIdx.x * 4 + (threadIdx.x >> 6);
    int lane = threadIdx.x & 63;
    const float4* xp = (const float4*)(x + (size_t)row * D_);
    float4 v0 = xp[lane];
    float4 v1 = xp[lane + 64];
    float s  = v0.x + v0.y + v0.z + v0.w + v1.x + v1.y + v1.z + v1.w;
    float sq = v0.x*v0.x + v0.y*v0.y + v0.z*v0.z + v0.w*v0.w
             + v1.x*v1.x + v1.y*v1.y + v1.z*v1.z + v1.w*v1.w;
    #pragma unroll
    for (int o = 32; o; o >>= 1) { s += __shfl_xor(s, o); sq += __shfl_xor(sq, o); }
    float mu   = s * (1.0f / D_);
    float var  = sq * (1.0f / D_) - mu * mu;
    float rstd = rsqrtf(var + 1e-5f);
    const float4 wv0 = ((const float4*)w)[lane];
    const float4 wv1 = ((const float4*)w)[lane + 64];
    const float4 bv0 = ((const float4*)b)[lane];
    const float4 bv1 = ((const float4*)b)[lane + 64];
    ushort4 o0, o1;
    o0.x = f2bf((v0.x - mu) * rstd * wv0.x + bv0.x);
    o0.y = f2bf((v0.y - mu) * rstd * wv0.y + bv0.y);
    o0.z = f2bf((v0.z - mu) * rstd * wv0.z + bv0.z);
    o0.w = f2bf((v0.w - mu) * rstd * wv0.w + bv0.w);
    o1.x = f2bf((v1.x - mu) * rstd * wv1.x + bv1.x);
    o1.y = f2bf((v1.y - mu) * rstd * wv1.y + bv1.y);
    o1.z = f2bf((v1.z - mu) * rstd * wv1.z + bv1.z);
    o1.w = f2bf((v1.w - mu) * rstd * wv1.w + bv1.w);
    ((ushort4*)(xn + (size_t)row * D_))[lane]      = o0;
    ((ushort4*)(xn + (size_t)row * D_))[lane + 64] = o1;
}

// ---------------- transpose + cast f32 W[R][C] -> bf16 WT[C][R] ----------------
__global__ void transpose_cast_kernel(const float* __restrict__ W, ushort* __restrict__ WT,
                                      int R, int C) {
    int idx = blockIdx.x * blockDim.x + threadIdx.x;
    if (idx >= R * C) return;
    int r = idx / C, c = idx - r * C;
    WT[(size_t)c * R + r] = f2bf(W[idx]);
}

// ---------------- bf16 MFMA GEMM: 128x128 tile, BK=64, single buffer ----------------
// Raises MFMA-per-barrier: 32 MFMAs per K-step (vs 16 at BK=32) with the same
// 2-barrier cost; acc stays 4x4 (no VGPR cliff, unlike the 256-tile attempt).
// LDS [128][64] with 16B-chunk rotation pp=(c+(row&7))&7: per 16-lane read
// phase each lane hits a distinct 16B slot -> exactly 2 lanes/bank (free).
// Linear global_load_lds dest + inverse-rotated per-lane global source.
// Bijective XCD chunking, n-fastest 1D grid (verified R6/R7).
template<int KDIM, int NT, int EPI>
__global__ __launch_bounds__(256) void gemm_kernel(
        const ushort* __restrict__ A, const ushort* __restrict__ BT,
        ushort* __restrict__ qo, ushort* __restrict__ ko, ushort* __restrict__ vo,
        float* __restrict__ outp, const float* __restrict__ xres, const float* __restrict__ bout) {
    __shared__ __align__(16) ushort As[128 * 64];   // 16 KB
    __shared__ __align__(16) ushort Bs[128 * 64];   // 16 KB

    const int nwg = (int)gridDim.x;
    const int orig = (int)blockIdx.x;
    const int qd = nwg >> 3, rm = nwg & 7;
    const int xcd = orig & 7, loc = orig >> 3;
    const int wg = (xcd < rm ? xcd * (qd + 1) : rm * (qd + 1) + (xcd - rm) * qd) + loc;
    const int m0 = (wg / NT) * 128, n0 = (wg % NT) * 128;

    const int tid = threadIdx.x;
    const int lane = tid & 63, wave = tid >> 6;
    const int wm = (wave >> 1) * 64, wn = (wave & 1) * 64;
    const int fr = lane & 15;
    const int g  = lane >> 4;

    // staging: 16 segments of 1KB per tile (8 rows x 64 cols each); wave owns
    // segs 4w..4w+3 of each. Lane l -> row seg*8+(l>>3), 16B-pos pp=l&7;
    // global chunk c = (pp - (row&7)) & 7  (inverse rotation).
    const ushort* Ag[4]; const ushort* Bg[4];
    ushort* Al[4]; ushort* Bl[4];
    #pragma unroll
    for (int i = 0; i < 4; ++i) {
        int seg = wave * 4 + i;
        int row = seg * 8 + (lane >> 3);
        int pp  = lane & 7;
        int c   = (pp - (row & 7)) & 7;
        Ag[i] = A  + (size_t)(m0 + row) * KDIM + c * 8;
        Bg[i] = BT + (size_t)(n0 + row) * KDIM + c * 8;
        Al[i] = &As[seg * 512];
        Bl[i] = &Bs[seg * 512];
    }

    // read side: k-chunk c = kk*4 + g; stored at pp = (c + (fr&7)) & 7.
    const int rp0 = ((g + (fr & 7)) & 7) * 8;        // kk = 0
    const int rp1 = (((4 + g) + (fr & 7)) & 7) * 8;  // kk = 1

    f32x4 acc[4][4] = {};

    for (int k0 = 0; k0 < KDIM; k0 += 64) {
        __syncthreads();
        #pragma unroll
        for (int i = 0; i < 4; ++i) {
            GLD(Ag[i] + k0, Al[i]);
            GLD(Bg[i] + k0, Bl[i]);
        }
        __syncthreads();   // compiler drains vmcnt(0) before barrier
        #pragma unroll
        for (int kk = 0; kk < 2; ++kk) {
            const int rp = kk ? rp1 : rp0;
            bf16x8 af[4], bfv[4];
            #pragma unroll
            for (int i = 0; i < 4; ++i) {
                af[i]  = *(const bf16x8*)&As[(wm + i * 16 + fr) * 64 + rp];
                bfv[i] = *(const bf16x8*)&Bs[(wn + i * 16 + fr) * 64 + rp];
            }
            #pragma unroll
            for (int i = 0; i < 4; ++i)
                #pragma unroll
                for (int j = 0; j < 4; ++j)
                    acc[i][j] = __builtin_amdgcn_mfma_f32_16x16x32_bf16(af[i], bfv[j], acc[i][j], 0, 0, 0);
        }
    }

    #pragma unroll
    for (int i = 0; i < 4; ++i) {
        #pragma unroll
        for (int j = 0; j < 4; ++j) {
            #pragma unroll
            for (int rg = 0; rg < 4; ++rg) {
                int gr = m0 + wm + i * 16 + ((lane >> 4) << 2) + rg;
                int gc = n0 + wn + j * 16 + (lane & 15);
                float val = acc[i][j][rg];
                if (EPI == 0) {
                    int bb = gr / N_, ii = gr - bb * N_;
                    int part = gc / INNER_, rem = gc - part * INNER_;
                    int h = rem >> 6, d = rem & 63;
                    size_t di = (((size_t)bb * H_ + h) * N_ + ii) * DH_ + d;
                    if (part == 0)      qo[di] = f2bf(val * SCALE_);
                    else if (part == 1) ko[di] = f2bf(val);
                    else                vo[di] = f2bf(val);
                } else {
                    size_t oi = (size_t)gr * D_ + gc;
                    outp[oi] = val + bout[gc] + xres[oi];
                }
            }
        }
    }
}

// ---------------- landmark means over L=300 ----------------
__global__ __launch_bounds__(64) void landmark_kernel(const ushort* __restrict__ q,
        const ushort* __restrict__ k, float* __restrict__ qland, float* __restrict__ kland) {
    int bhm = blockIdx.x;
    int bh = bhm / M_, m = bhm - bh * M_;
    const ushort* src = (blockIdx.y == 0) ? q : k;
    float* dst = (blockIdx.y == 0) ? qland : kland;
    int d = threadIdx.x;
    const ushort* p = src + ((size_t)bh * N_ + m * L_) * DH_ + d;
    float s = 0.f;
    #pragma unroll 4
    for (int j = 0; j < L_; ++j) s += bf2f(p[(size_t)j * DH_]);
    dst[((size_t)bh * M_ + m) * DH_ + d] = s * (1.0f / L_);
}

// ---------------- attn2 = softmax(q_land k_land^T) + global max row/col sums ----------------
__global__ __launch_bounds__(512) void attn2_kernel(const float* __restrict__ qland,
        const float* __restrict__ kland, float* __restrict__ attn2, unsigned* __restrict__ gmax) {
    int bh = blockIdx.x;
    __shared__ float sim[M_ * M_];
    int t = threadIdx.x;
    if (t < M_ * M_) {
        int i = t / M_, j = t - (t / M_) * M_;
        const float* qp = qland + ((size_t)bh * M_ + i) * DH_;
        const float* kp = kland + ((size_t)bh * M_ + j) * DH_;
        float s = 0.f;
        for (int d = 0; d < DH_; ++d) s += qp[d] * kp[d];
        sim[t] = s;
    }
    __syncthreads();
    if (t < M_) {
        float mx = -1e30f;
        for (int j = 0; j < M_; ++j) mx = fmaxf(mx, sim[t * M_ + j]);
        float s = 0.f;
        for (int j = 0; j < M_; ++j) { float e = __expf(sim[t * M_ + j] - mx); sim[t * M_ + j] = e; s += e; }
        float inv = 1.0f / s;
        for (int j = 0; j < M_; ++j) sim[t * M_ + j] *= inv;
    }
    __syncthreads();
    if (t < M_ * M_) attn2[(size_t)bh * 400 + t] = sim[t];
    if (t < M_) {
        float cs = 0.f, rs = 0.f;
        for (int i = 0; i < M_; ++i) { cs += sim[i * M_ + t]; rs += sim[t * M_ + i]; }
        atomicMax(&gmax[1], __float_as_uint(cs));
        atomicMax(&gmax[0], __float_as_uint(rs));
    }
}

// ---------------- Newton-Schulz pinv, 6 iters, 20x20 per (b,h) ----------------
__global__ __launch_bounds__(512) void pinv_kernel(const float* __restrict__ attn2,
        const unsigned* __restrict__ gmax, float* __restrict__ ainv) {
    int bh = blockIdx.x;
    __shared__ float buf[5 * 400];
    float* pa = buf; float* pz = buf + 400; float* m1 = buf + 800; float* m2 = buf + 1200; float* m3 = buf + 1600;
    int t = threadIdx.x;
    float rden = 1.0f / (__uint_as_float(gmax[0]) * __uint_as_float(gmax[1]));
    int i = t / M_, j = t - (t / M_) * M_;
    if (t < 400) {
        pa[t] = attn2[(size_t)bh * 400 + t];
        pz[t] = attn2[(size_t)bh * 400 + j * M_ + i] * rden;   // a^T / denom
    }
    for (int it = 0; it < 6; ++it) {
        __syncthreads();
        if (t < 400) { float s = 0; for (int kk = 0; kk < M_; ++kk) s += pa[i * M_ + kk] * pz[kk * M_ + j]; m1[t] = s; }
        __syncthreads();
        if (t < 400) { float s = 0; for (int kk = 0; kk < M_; ++kk) s += m1[i * M_ + kk] * m1[kk * M_ + j]; m2[t] = 7.0f * m1[t] - s; }
        __syncthreads();
        if (t < 400) { float s = 0; for (int kk = 0; kk < M_; ++kk) s += m1[i * M_ + kk] * m2[kk * M_ + j]; m3[t] = 15.0f * m1[t] - s; }
        __syncthreads();
        if (t < 400) { float s = 0; for (int kk = 0; kk < M_; ++kk) s += pz[i * M_ + kk] * m3[kk * M_ + j]; m2[t] = 0.25f * (13.0f * pz[t] - s); }
        __syncthreads();
        float* tmp = pz; pz = m2; m2 = tmp;
    }
    if (t < 400) ainv[(size_t)bh * 400 + t] = pz[t];
}

// ---------------- attn3@v chunk partials via MFMA (R11 verified) ----------------
__global__ __launch_bounds__(256) void attn3v_mfma_kernel(
        const float* __restrict__ qland, const ushort* __restrict__ k,
        const ushort* __restrict__ v, float* __restrict__ pacc, float* __restrict__ pden) {
    int ch = blockIdx.x, bh = blockIdx.y;
    __shared__ __align__(16) ushort Ks[CH2_ * 64];    // 16 KB, chunk-rotated rows
    __shared__ __align__(16) ushort Vs[CH2_ * 64];    // 16 KB
    __shared__ __align__(16) ushort qlb[32 * 64];     // 4 KB, rows >=20 zero
    __shared__ __align__(16) ushort Pt[32 * 136];     // 8.5 KB, rotated, 8-pad
    int t = threadIdx.x;
    int lane = t & 63, wave = t >> 6;
    int j0 = ch * CH2_;
    int jmax = N_ - j0; if (jmax > CH2_) jmax = CH2_;

    const ushort* kbase = k + ((size_t)bh * N_ + j0) * DH_;
    const ushort* vbase = v + ((size_t)bh * N_ + j0) * DH_;
    #pragma unroll
    for (int i = 0; i < 4; ++i) {
        int pdx = (wave * 4 + i) * 64 + lane;
        int row = pdx >> 3, pp = pdx & 7;
        int c = (pp - (row & 7)) & 7;
        int rowc = row < jmax ? row : jmax - 1;
        GLD(kbase + (size_t)rowc * DH_ + c * 8, &Ks[pdx * 8]);
        GLD(vbase + (size_t)rowc * DH_ + c * 8, &Vs[pdx * 8]);
    }
    {
        int row = t >> 3, pp = t & 7;
        int c = (pp - (row & 7)) & 7;
        ushort w8[8];
        if (row < M_) {
            const float* qp = qland + ((size_t)bh * M_ + row) * DH_ + c * 8;
            #pragma unroll
            for (int e = 0; e < 8; ++e) w8[e] = f2bf(qp[e]);
        } else {
            #pragma unroll
            for (int e = 0; e < 8; ++e) w8[e] = 0;
        }
        *(uint4*)&qlb[t * 8] = *(const uint4*)w8;
    }
    __syncthreads();

    int fr = lane & 15, g = lane >> 4;

    f32x4 sacc[2][2] = {};
    #pragma unroll
    for (int ks = 0; ks < 2; ++ks) {
        bf16x8 bq[2];
        #pragma unroll
        for (int mt = 0; mt < 2; ++mt) {
            int m = mt * 16 + fr;
            int c = ks * 4 + g;
            int pp = (c + (m & 7)) & 7;
            bq[mt] = *(const bf16x8*)&qlb[m * 64 + pp * 8];
        }
        #pragma unroll
        for (int jl = 0; jl < 2; ++jl) {
            int row = (wave * 2 + jl) * 16 + fr;
            int c = ks * 4 + g;
            int pp = (c + (row & 7)) & 7;
            bf16x8 ak = *(const bf16x8*)&Ks[row * 64 + pp * 8];
            #pragma unroll
            for (int mt = 0; mt < 2; ++mt)
                sacc[jl][mt] = __builtin_amdgcn_mfma_f32_16x16x32_bf16(ak, bq[mt], sacc[jl][mt], 0, 0, 0);
        }
    }
    #pragma unroll
    for (int jl = 0; jl < 2; ++jl) {
        #pragma unroll
        for (int mt = 0; mt < 2; ++mt) {
            int m = mt * 16 + fr;
            #pragma unroll
            for (int rg = 0; rg < 4; ++rg) {
                int jloc = (wave * 2 + jl) * 16 + 4 * g + rg;
                float e = __expf(sacc[jl][mt][rg]);
                e = (jloc < jmax) ? e : 0.f;
                int c = jloc >> 3;
                int pp = (c & 8) | ((c + (m & 7)) & 7);
                Pt[m * 136 + pp * 8 + (jloc & 7)] = f2bf(e);
            }
        }
    }
    __syncthreads();

    if (t < M_) {
        float s = 0.f;
        #pragma unroll
        for (int cc = 0; cc < 16; ++cc) {
            bf16x8 pv = *(const bf16x8*)&Pt[t * 136 + cc * 8];
            #pragma unroll
            for (int e = 0; e < 8; ++e) s += (float)pv[e];
        }
        pden[((size_t)bh * NCH2_ + ch) * M_ + t] = s;
    }

    f32x4 oacc[2] = {};
    int d = wave * 16 + fr;
    int cch = d >> 3, drem = d & 7;
    #pragma unroll
    for (int ks = 0; ks < 4; ++ks) {
        ushort bw[8];
        #pragma unroll
        for (int e = 0; e < 8; ++e) {
            int j = ks * 32 + g * 8 + e;
            int pp = (cch + (j & 7)) & 7;
            bw[e] = Vs[j * 64 + pp * 8 + drem];
        }
        bf16x8 bv = *(const bf16x8*)bw;
        #pragma unroll
        for (int mt = 0; mt < 2; ++mt) {
            int m = mt * 16 + fr;
            int c = ks * 4 + g;
            int pp = (c & 8) | ((c + (m & 7)) & 7);
            bf16x8 ap = *(const bf16x8*)&Pt[m * 136 + pp * 8];
            oacc[mt] = __builtin_amdgcn_mfma_f32_16x16x32_bf16(ap, bv, oacc[mt], 0, 0, 0);
        }
    }
    #pragma unroll
    for (int mt = 0; mt < 2; ++mt) {
        #pragma unroll
        for (int rg = 0; rg < 4; ++rg) {
            int m = mt * 16 + 4 * g + rg;
            if (m < M_)
                pacc[(((size_t)bh * NCH2_ + ch) * M_ + m) * DH_ + d] = oacc[mt][rg];
        }
    }
}

// ---------------- reduce partials -> kv, then akv = ainv @ kv ----------------
__global__ __launch_bounds__(256) void akv_kernel(const float* __restrict__ ainv,
        const float* __restrict__ pacc, const float* __restrict__ pden,
        float* __restrict__ akv) {
    int bh = blockIdx.x;
    __shared__ float kvs[M_ * DH_];
    __shared__ float inv_s[M_ * M_];
    __shared__ float den[M_];
    int t = threadIdx.x;
    for (int i = t; i < M_ * M_; i += 256) inv_s[i] = ainv[(size_t)bh * 400 + i];
    if (t < M_) {
        float s = 0.f;
        for (int c = 0; c < NCH2_; ++c) s += pden[((size_t)bh * NCH2_ + c) * M_ + t];
        den[t] = s;
    }
    __syncthreads();
    for (int idx = t; idx < M_ * DH_; idx += 256) {
        int m = idx >> 6;
        float s = 0.f;
        #pragma unroll 4
        for (int c = 0; c < NCH2_; ++c) s += pacc[((size_t)bh * NCH2_ + c) * M_ * DH_ + idx];
        kvs[idx] = s / den[m];
    }
    __syncthreads();
    for (int idx = t; idx < M_ * DH_; idx += 256) {
        int m = idx >> 6, d = idx & 63;
        float s = 0.f;
        #pragma unroll
        for (int mm = 0; mm < M_; ++mm) s += inv_s[m * M_ + mm] * kvs[mm * DH_ + d];
        akv[(size_t)bh * M_ * DH_ + idx] = s;
    }
}

// ---------------- fused conv + attention epilogue, 64 rows per block ----------------
__global__ __launch_bounds__(256) void out_attn_kernel(const ushort* __restrict__ q,
        const ushort* __restrict__ v, const float* __restrict__ kland,
        const float* __restrict__ akv, const float* __restrict__ resk,
        ushort* __restrict__ att_out) {
    int bh = blockIdx.y;
    int b = bh / H_, h = bh - b * H_;
    int r0 = blockIdx.x * 64;
    __shared__ ushort Vs[96 * 64];      // 12 KB, rows r0-16 .. r0+79, zero-padded
    __shared__ float  Cs[64 * 65];      // 16.6 KB conv result, padded stride
    __shared__ float  klf[M_ * DH_];    // 5 KB
    __shared__ float  akvs[M_ * DH_];   // 5 KB
    int t = threadIdx.x;

    const ushort* vbase = v + (size_t)bh * N_ * DH_;
    #pragma unroll
    for (int i = 0; i < 3; ++i) {
        int c2 = t + i * 256;              // 768 16B-chunks total
        int row = c2 >> 3, ch = c2 & 7;
        int gr = r0 - 16 + row;
        uint4 val = make_uint4(0u, 0u, 0u, 0u);
        if (gr >= 0 && gr < N_) val = *(const uint4*)(vbase + (size_t)gr * DH_ + ch * 8);
        *(uint4*)&Vs[row * 64 + ch * 8] = val;
    }
    for (int i = t; i < M_ * DH_; i += 256) {
        klf[i]  = kland[(size_t)bh * M_ * DH_ + i];
        akvs[i] = akv[(size_t)bh * M_ * DH_ + i];
    }
    // taps: uniform global loads -> SGPRs
    float kr[KW_];
    #pragma unroll
    for (int tt = 0; tt < KW_; ++tt) kr[tt] = resk[h * KW_ + tt];
    __syncthreads();

    {   // conv phase
        int g = t >> 6, d = t & 63;
        float vv[48];
        #pragma unroll
        for (int j = 0; j < 48; ++j) vv[j] = bf2f(Vs[(g * 16 + j) * 64 + d]);
        #pragma unroll
        for (int rr = 0; rr < 16; ++rr) {
            float s = 0.f;
            #pragma unroll
            for (int tt = 0; tt < KW_; ++tt) s += kr[tt] * vv[rr + tt];
            Cs[(g * 16 + rr) * 65 + d] = s;
        }
    }
    __syncthreads();

    // attention phase
    int rr = t >> 2, quad = t & 3;
    int r = r0 + rr;
    bool valid = r < N_;
    int rc = valid ? r : N_ - 1;

    float qf[16];
    const uint4* qp = (const uint4*)(q + ((size_t)bh * N_ + rc) * DH_ + quad * 16);
    #pragma unroll
    for (int c = 0; c < 2; ++c) {
        uint4 u = qp[c];
        qf[c*8+0] = bf2f((ushort)(u.x & 0xFFFF)); qf[c*8+1] = bf2f((ushort)(u.x >> 16));
        qf[c*8+2] = bf2f((ushort)(u.y & 0xFFFF)); qf[c*8+3] = bf2f((ushort)(u.y >> 16));
        qf[c*8+4] = bf2f((ushort)(u.z & 0xFFFF)); qf[c*8+5] = bf2f((ushort)(u.z >> 16));
        qf[c*8+6] = bf2f((ushort)(u.w & 0xFFFF)); qf[c*8+7] = bf2f((ushort)(u.w >> 16));
    }

    float p[M_];
    #pragma unroll
    for (int m = 0; m < M_; ++m) {
        const float* kl = &klf[m * DH_ + quad * 16];
        float s = 0.f;
        #pragma unroll
        for (int dd = 0; dd < 16; ++dd) s += qf[dd] * kl[dd];
        s += __shfl_xor(s, 1);       // combine the 4 quads of this row
        s += __shfl_xor(s, 2);
        p[m] = s;
    }
    float mx = -1e30f;
    #pragma unroll
    for (int m = 0; m < M_; ++m) mx = fmaxf(mx, p[m]);
    float ssum = 0.f;
    #pragma unroll
    for (int m = 0; m < M_; ++m) { p[m] = __expf(p[m] - mx); ssum += p[m]; }
    float rinv = 1.0f / ssum;
    #pragma unroll
    for (int m = 0; m < M_; ++m) p[m] *= rinv;

    float out[16];
    #pragma unroll
    for (int dd = 0; dd < 16; ++dd) out[dd] = Cs[rr * 65 + quad * 16 + dd];
    #pragma unroll
    for (int m = 0; m < M_; ++m) {
        float w = p[m];
        const float* av = &akvs[m * DH_ + quad * 16];
        #pragma unroll
        for (int dd = 0; dd < 16; ++dd) out[dd] += w * av[dd];
    }

    if (valid) {
        ushort* op = att_out + ((size_t)(b * N_ + r)) * INNER_ + h * DH_ + quad * 16;
        #pragma unroll
        for (int c = 0; c < 2; ++c) {
            uint4 w4;
            w4.x = (unsigned)f2bf(out[c*8+0]) | ((unsigned)f2bf(out[c*8+1]) << 16);
            w4.y = (unsigned)f2bf(out[c*8+2]) | ((unsigned)f2bf(out[c*8+3]) << 16);
            w4.z = (unsigned)f2bf(out[c*8+4]) | ((unsigned)f2bf(out[c*8+5]) << 16);
            w4.w = (unsigned)f2bf(out[c*8+6]) | ((unsigned)f2bf(out[c*8+7]) << 16);
            ((uint4*)op)[c] = w4;
        }
    }
}

// ---------------- launcher ----------------
extern "C" void kernel_launch(void* const* d_in, const int* in_sizes, int n_in,
                              void* d_out, int out_size, void* d_ws, size_t ws_size,
                              hipStream_t stream) {
    const float* x      = (const float*)d_in[0];
    const float* norm_w = (const float*)d_in[1];
    const float* norm_b = (const float*)d_in[2];
    const float* w_qkv  = (const float*)d_in[3];
    const float* w_out  = (const float*)d_in[4];
    const float* b_out  = (const float*)d_in[5];
    const float* res_k  = (const float*)d_in[6];

    char* wsp = (char*)d_ws;
    size_t off = 0;
    auto alloc = [&](size_t bytes) -> void* {
        void* p = wsp + off;
        off = (off + bytes + 255) & ~(size_t)255;
        return p;
    };
    ushort* xn    = (ushort*)alloc((size_t)ROWS_ * D_ * 2);          // 98.3 MB (reused as att_out)
    ushort* qb    = (ushort*)alloc((size_t)B_ * H_ * N_ * DH_ * 2);  // 73.7 MB
    ushort* kb    = (ushort*)alloc((size_t)B_ * H_ * N_ * DH_ * 2);
    ushort* vb    = (ushort*)alloc((size_t)B_ * H_ * N_ * DH_ * 2);
    ushort* wqkvT = (ushort*)alloc((size_t)3 * INNER_ * D_ * 2);
    ushort* woutT = (ushort*)alloc((size_t)D_ * INNER_ * 2);
    float*  qland = (float*)alloc((size_t)B_ * H_ * M_ * DH_ * 4);
    float*  kland = (float*)alloc((size_t)B_ * H_ * M_ * DH_ * 4);
    float*  attn2 = (float*)alloc((size_t)B_ * H_ * 400 * 4);
    float*  ainv  = (float*)alloc((size_t)B_ * H_ * 400 * 4);
    float*  pacc  = (float*)alloc((size_t)B_ * H_ * NCH2_ * M_ * DH_ * 4);  // 23.1 MB
    float*  pden  = (float*)alloc((size_t)B_ * H_ * NCH2_ * M_ * 4);
    float*  akvb  = (float*)alloc((size_t)B_ * H_ * M_ * DH_ * 4);
    unsigned* gmx = (unsigned*)alloc(256);
    ushort* att_out = xn;   // xn dead after QKV GEMM

    hipMemsetAsync(gmx, 0, 8, stream);

    int tn = 3 * INNER_ * D_;
    transpose_cast_kernel<<<(tn + 255) / 256, 256, 0, stream>>>(w_qkv, wqkvT, D_, 3 * INNER_);
    tn = D_ * INNER_;
    transpose_cast_kernel<<<(tn + 255) / 256, 256, 0, stream>>>(w_out, woutT, INNER_, D_);

    ln_kernel<<<ROWS_ / 4, 256, 0, stream>>>(x, norm_w, norm_b, xn);

    gemm_kernel<D_, 9, 0><<<(ROWS_ / 128) * 9, 256, 0, stream>>>(
        xn, wqkvT, qb, kb, vb, nullptr, nullptr, nullptr);

    landmark_kernel<<<dim3(B_ * H_ * M_, 2), 64, 0, stream>>>(qb, kb, qland, kland);

    attn2_kernel<<<B_ * H_, 512, 0, stream>>>(qland, kland, attn2, gmx);
    pinv_kernel<<<B_ * H_, 512, 0, stream>>>(attn2, gmx, ainv);

    attn3v_mfma_kernel<<<dim3(NCH2_, B_ * H_), 256, 0, stream>>>(qland, kb, vb, pacc, pden);

    akv_kernel<<<B_ * H_, 256, 0, stream>>>(ainv, pacc, pden, akvb);

    out_attn_kernel<<<dim3((N_ + 63) / 64, B_ * H_), 256, 0, stream>>>(
        qb, vb, kland, akvb, res_k, att_out);

    gemm_kernel<INNER_, 4, 1><<<(ROWS_ / 128) * 4, 256, 0, stream>>>(
        att_out, woutT, nullptr, nullptr, nullptr, (float*)d_out, x, b_out);
}

// Round 14
// 608.767 us; speedup vs baseline: 1.0368x; 1.0368x over previous
//
#include <hip/hip_runtime.h>

typedef float  f32x4  __attribute__((ext_vector_type(4)));
typedef __bf16 bf16x4 __attribute__((ext_vector_type(4)));
typedef __bf16 bf16x8 __attribute__((ext_vector_type(8)));

#define B_     16
#define N_     6000
#define D_     512
#define H_     6
#define DH_    64
#define INNER_ 384
#define M_     20
#define L_     300
#define KW_    33
#define ROWS_  (B_ * N_)     // 96000
#define SCALE_ 0.125f        // 64^-0.5
#define CH2_   128           // attn3 chunk rows (MFMA version)
#define NCH2_  47            // ceil(6000/128)

__device__ __forceinline__ ushort f2bf(float f) {
    __bf16 h = (__bf16)f;                    // v_cvt (RNE)
    return __builtin_bit_cast(ushort, h);
}
__device__ __forceinline__ float bf2f(ushort h) {
    return __uint_as_float(((unsigned)h) << 16);
}

// async global->LDS, 16B per lane; LDS dest = wave-uniform base + lane*16
#define GLD(gp, lp) __builtin_amdgcn_global_load_lds( \
    (const __attribute__((address_space(1))) unsigned int*)(gp), \
    (__attribute__((address_space(3))) unsigned int*)(lp), 16, 0, 0)

// ---------------- LayerNorm: wave-per-row, shfl-only, no LDS ----------------
__global__ __launch_bounds__(256) void ln_kernel(const float* __restrict__ x,
        const float* __restrict__ w, const float* __restrict__ b,
        ushort* __restrict__ xn) {
    int row  = blockIdx.x * 4 + (threadIdx.x >> 6);
    int lane = threadIdx.x & 63;
    const float4* xp = (const float4*)(x + (size_t)row * D_);
    float4 v0 = xp[lane];
    float4 v1 = xp[lane + 64];
    float s  = v0.x + v0.y + v0.z + v0.w + v1.x + v1.y + v1.z + v1.w;
    float sq = v0.x*v0.x + v0.y*v0.y + v0.z*v0.z + v0.w*v0.w
             + v1.x*v1.x + v1.y*v1.y + v1.z*v1.z + v1.w*v1.w;
    #pragma unroll
    for (int o = 32; o; o >>= 1) { s += __shfl_xor(s, o); sq += __shfl_xor(sq, o); }
    float mu   = s * (1.0f / D_);
    float var  = sq * (1.0f / D_) - mu * mu;
    float rstd = rsqrtf(var + 1e-5f);
    const float4 wv0 = ((const float4*)w)[lane];
    const float4 wv1 = ((const float4*)w)[lane + 64];
    const float4 bv0 = ((const float4*)b)[lane];
    const float4 bv1 = ((const float4*)b)[lane + 64];
    ushort4 o0, o1;
    o0.x = f2bf((v0.x - mu) * rstd * wv0.x + bv0.x);
    o0.y = f2bf((v0.y - mu) * rstd * wv0.y + bv0.y);
    o0.z = f2bf((v0.z - mu) * rstd * wv0.z + bv0.z);
    o0.w = f2bf((v0.w - mu) * rstd * wv0.w + bv0.w);
    o1.x = f2bf((v1.x - mu) * rstd * wv1.x + bv1.x);
    o1.y = f2bf((v1.y - mu) * rstd * wv1.y + bv1.y);
    o1.z = f2bf((v1.z - mu) * rstd * wv1.z + bv1.z);
    o1.w = f2bf((v1.w - mu) * rstd * wv1.w + bv1.w);
    ((ushort4*)(xn + (size_t)row * D_))[lane]      = o0;
    ((ushort4*)(xn + (size_t)row * D_))[lane + 64] = o1;
}

// ---------------- transpose + cast f32 W[R][C] -> bf16 WT[C][R] ----------------
__global__ void transpose_cast_kernel(const float* __restrict__ W, ushort* __restrict__ WT,
                                      int R, int C) {
    int idx = blockIdx.x * blockDim.x + threadIdx.x;
    if (idx >= R * C) return;
    int r = idx / C, c = idx - r * C;
    WT[(size_t)c * R + r] = f2bf(W[idx]);
}

// ---------------- bf16 MFMA GEMM (R7 verified structure, 128x128, BK=32) ----------------
// Single-buffer global_load_lds staging, 16B-chunk rotation swizzle
// (bank-conflict-free, measured 0), bijective XCD chunking, n-fastest 1D grid.
// Structure ceiling verified: dbuf (R8), 256-tile (R10), triple-buffer counted
// vmcnt (R12), BK=64 (R13) all neutral-or-worse. Do not re-attempt.
template<int KDIM, int NT, int EPI>
__global__ __launch_bounds__(256) void gemm_kernel(
        const ushort* __restrict__ A, const ushort* __restrict__ BT,
        ushort* __restrict__ qo, ushort* __restrict__ ko, ushort* __restrict__ vo,
        float* __restrict__ outp, const float* __restrict__ xres, const float* __restrict__ bout) {
    __shared__ __align__(16) ushort As[128 * 32];
    __shared__ __align__(16) ushort Bs[128 * 32];

    const int nwg = (int)gridDim.x;
    const int orig = (int)blockIdx.x;
    const int qd = nwg >> 3, rm = nwg & 7;
    const int xcd = orig & 7, loc = orig >> 3;
    const int wg = (xcd < rm ? xcd * (qd + 1) : rm * (qd + 1) + (xcd - rm) * qd) + loc;
    const int m0 = (wg / NT) * 128, n0 = (wg % NT) * 128;

    const int tid = threadIdx.x;
    const int lane = tid & 63, wave = tid >> 6;
    const int wm = (wave >> 1) * 64, wn = (wave & 1) * 64;
    const int fr = lane & 15;

    const int seg0 = wave * 2, seg1 = wave * 2 + 1;
    const int srow0 = seg0 * 16 + (lane >> 2);
    const int srow1 = seg1 * 16 + (lane >> 2);
    const int scol  = ((((lane & 3) - ((lane >> 3) & 3)) & 3) * 8);
    const ushort* Ag0 = A  + (size_t)(m0 + srow0) * KDIM + scol;
    const ushort* Ag1 = A  + (size_t)(m0 + srow1) * KDIM + scol;
    const ushort* Bg0 = BT + (size_t)(n0 + srow0) * KDIM + scol;
    const ushort* Bg1 = BT + (size_t)(n0 + srow1) * KDIM + scol;
    ushort* Al0 = &As[seg0 * 512];
    ushort* Al1 = &As[seg1 * 512];
    ushort* Bl0 = &Bs[seg0 * 512];
    ushort* Bl1 = &Bs[seg1 * 512];

    const int rp = (((lane >> 4) + (fr >> 1)) & 3) * 8;

    f32x4 acc[4][4] = {};

    for (int k0 = 0; k0 < KDIM; k0 += 32) {
        __syncthreads();
        GLD(Ag0 + k0, Al0);
        GLD(Ag1 + k0, Al1);
        GLD(Bg0 + k0, Bl0);
        GLD(Bg1 + k0, Bl1);
        __syncthreads();   // compiler drains vmcnt(0) before barrier
        bf16x8 af[4], bfv[4];
        #pragma unroll
        for (int i = 0; i < 4; ++i) {
            af[i]  = *(const bf16x8*)&As[(wm + i * 16 + fr) * 32 + rp];
            bfv[i] = *(const bf16x8*)&Bs[(wn + i * 16 + fr) * 32 + rp];
        }
        #pragma unroll
        for (int i = 0; i < 4; ++i)
            #pragma unroll
            for (int j = 0; j < 4; ++j)
                acc[i][j] = __builtin_amdgcn_mfma_f32_16x16x32_bf16(af[i], bfv[j], acc[i][j], 0, 0, 0);
    }

    #pragma unroll
    for (int i = 0; i < 4; ++i) {
        #pragma unroll
        for (int j = 0; j < 4; ++j) {
            #pragma unroll
            for (int rg = 0; rg < 4; ++rg) {
                int gr = m0 + wm + i * 16 + ((lane >> 4) << 2) + rg;
                int gc = n0 + wn + j * 16 + (lane & 15);
                float val = acc[i][j][rg];
                if (EPI == 0) {
                    int bb = gr / N_, ii = gr - bb * N_;
                    int part = gc / INNER_, rem = gc - part * INNER_;
                    int h = rem >> 6, d = rem & 63;
                    size_t di = (((size_t)bb * H_ + h) * N_ + ii) * DH_ + d;
                    if (part == 0)      qo[di] = f2bf(val * SCALE_);
                    else if (part == 1) ko[di] = f2bf(val);
                    else                vo[di] = f2bf(val);
                } else {
                    size_t oi = (size_t)gr * D_ + gc;
                    outp[oi] = val + bout[gc] + xres[oi];
                }
            }
        }
    }
}

// ---------------- landmark means over L=300 ----------------
__global__ __launch_bounds__(64) void landmark_kernel(const ushort* __restrict__ q,
        const ushort* __restrict__ k, float* __restrict__ qland, float* __restrict__ kland) {
    int bhm = blockIdx.x;
    int bh = bhm / M_, m = bhm - bh * M_;
    const ushort* src = (blockIdx.y == 0) ? q : k;
    float* dst = (blockIdx.y == 0) ? qland : kland;
    int d = threadIdx.x;
    const ushort* p = src + ((size_t)bh * N_ + m * L_) * DH_ + d;
    float s = 0.f;
    #pragma unroll 4
    for (int j = 0; j < L_; ++j) s += bf2f(p[(size_t)j * DH_]);
    dst[((size_t)bh * M_ + m) * DH_ + d] = s * (1.0f / L_);
}

// ---------------- attn2 = softmax(q_land k_land^T) + global max row/col sums ----------------
__global__ __launch_bounds__(512) void attn2_kernel(const float* __restrict__ qland,
        const float* __restrict__ kland, float* __restrict__ attn2, unsigned* __restrict__ gmax) {
    int bh = blockIdx.x;
    __shared__ float sim[M_ * M_];
    int t = threadIdx.x;
    if (t < M_ * M_) {
        int i = t / M_, j = t - (t / M_) * M_;
        const float* qp = qland + ((size_t)bh * M_ + i) * DH_;
        const float* kp = kland + ((size_t)bh * M_ + j) * DH_;
        float s = 0.f;
        for (int d = 0; d < DH_; ++d) s += qp[d] * kp[d];
        sim[t] = s;
    }
    __syncthreads();
    if (t < M_) {
        float mx = -1e30f;
        for (int j = 0; j < M_; ++j) mx = fmaxf(mx, sim[t * M_ + j]);
        float s = 0.f;
        for (int j = 0; j < M_; ++j) { float e = __expf(sim[t * M_ + j] - mx); sim[t * M_ + j] = e; s += e; }
        float inv = 1.0f / s;
        for (int j = 0; j < M_; ++j) sim[t * M_ + j] *= inv;
    }
    __syncthreads();
    if (t < M_ * M_) attn2[(size_t)bh * 400 + t] = sim[t];
    if (t < M_) {
        float cs = 0.f, rs = 0.f;
        for (int i = 0; i < M_; ++i) { cs += sim[i * M_ + t]; rs += sim[t * M_ + i]; }
        atomicMax(&gmax[1], __float_as_uint(cs));
        atomicMax(&gmax[0], __float_as_uint(rs));
    }
}

// ---------------- Newton-Schulz pinv, 6 iters, 20x20 per (b,h) ----------------
__global__ __launch_bounds__(512) void pinv_kernel(const float* __restrict__ attn2,
        const unsigned* __restrict__ gmax, float* __restrict__ ainv) {
    int bh = blockIdx.x;
    __shared__ float buf[5 * 400];
    float* pa = buf; float* pz = buf + 400; float* m1 = buf + 800; float* m2 = buf + 1200; float* m3 = buf + 1600;
    int t = threadIdx.x;
    float rden = 1.0f / (__uint_as_float(gmax[0]) * __uint_as_float(gmax[1]));
    int i = t / M_, j = t - (t / M_) * M_;
    if (t < 400) {
        pa[t] = attn2[(size_t)bh * 400 + t];
        pz[t] = attn2[(size_t)bh * 400 + j * M_ + i] * rden;   // a^T / denom
    }
    for (int it = 0; it < 6; ++it) {
        __syncthreads();
        if (t < 400) { float s = 0; for (int kk = 0; kk < M_; ++kk) s += pa[i * M_ + kk] * pz[kk * M_ + j]; m1[t] = s; }
        __syncthreads();
        if (t < 400) { float s = 0; for (int kk = 0; kk < M_; ++kk) s += m1[i * M_ + kk] * m1[kk * M_ + j]; m2[t] = 7.0f * m1[t] - s; }
        __syncthreads();
        if (t < 400) { float s = 0; for (int kk = 0; kk < M_; ++kk) s += m1[i * M_ + kk] * m2[kk * M_ + j]; m3[t] = 15.0f * m1[t] - s; }
        __syncthreads();
        if (t < 400) { float s = 0; for (int kk = 0; kk < M_; ++kk) s += pz[i * M_ + kk] * m3[kk * M_ + j]; m2[t] = 0.25f * (13.0f * pz[t] - s); }
        __syncthreads();
        float* tmp = pz; pz = m2; m2 = tmp;
    }
    if (t < 400) ainv[(size_t)bh * 400 + t] = pz[t];
}

// ---------------- attn3@v chunk partials via MFMA (R11 verified) ----------------
__global__ __launch_bounds__(256) void attn3v_mfma_kernel(
        const float* __restrict__ qland, const ushort* __restrict__ k,
        const ushort* __restrict__ v, float* __restrict__ pacc, float* __restrict__ pden) {
    int ch = blockIdx.x, bh = blockIdx.y;
    __shared__ __align__(16) ushort Ks[CH2_ * 64];    // 16 KB, chunk-rotated rows
    __shared__ __align__(16) ushort Vs[CH2_ * 64];    // 16 KB
    __shared__ __align__(16) ushort qlb[32 * 64];     // 4 KB, rows >=20 zero
    __shared__ __align__(16) ushort Pt[32 * 136];     // 8.5 KB, rotated, 8-pad
    int t = threadIdx.x;
    int lane = t & 63, wave = t >> 6;
    int j0 = ch * CH2_;
    int jmax = N_ - j0; if (jmax > CH2_) jmax = CH2_;

    const ushort* kbase = k + ((size_t)bh * N_ + j0) * DH_;
    const ushort* vbase = v + ((size_t)bh * N_ + j0) * DH_;
    #pragma unroll
    for (int i = 0; i < 4; ++i) {
        int pdx = (wave * 4 + i) * 64 + lane;
        int row = pdx >> 3, pp = pdx & 7;
        int c = (pp - (row & 7)) & 7;
        int rowc = row < jmax ? row : jmax - 1;
        GLD(kbase + (size_t)rowc * DH_ + c * 8, &Ks[pdx * 8]);
        GLD(vbase + (size_t)rowc * DH_ + c * 8, &Vs[pdx * 8]);
    }
    {
        int row = t >> 3, pp = t & 7;
        int c = (pp - (row & 7)) & 7;
        ushort w8[8];
        if (row < M_) {
            const float* qp = qland + ((size_t)bh * M_ + row) * DH_ + c * 8;
            #pragma unroll
            for (int e = 0; e < 8; ++e) w8[e] = f2bf(qp[e]);
        } else {
            #pragma unroll
            for (int e = 0; e < 8; ++e) w8[e] = 0;
        }
        *(uint4*)&qlb[t * 8] = *(const uint4*)w8;
    }
    __syncthreads();

    int fr = lane & 15, g = lane >> 4;

    f32x4 sacc[2][2] = {};
    #pragma unroll
    for (int ks = 0; ks < 2; ++ks) {
        bf16x8 bq[2];
        #pragma unroll
        for (int mt = 0; mt < 2; ++mt) {
            int m = mt * 16 + fr;
            int c = ks * 4 + g;
            int pp = (c + (m & 7)) & 7;
            bq[mt] = *(const bf16x8*)&qlb[m * 64 + pp * 8];
        }
        #pragma unroll
        for (int jl = 0; jl < 2; ++jl) {
            int row = (wave * 2 + jl) * 16 + fr;
            int c = ks * 4 + g;
            int pp = (c + (row & 7)) & 7;
            bf16x8 ak = *(const bf16x8*)&Ks[row * 64 + pp * 8];
            #pragma unroll
            for (int mt = 0; mt < 2; ++mt)
                sacc[jl][mt] = __builtin_amdgcn_mfma_f32_16x16x32_bf16(ak, bq[mt], sacc[jl][mt], 0, 0, 0);
        }
    }
    #pragma unroll
    for (int jl = 0; jl < 2; ++jl) {
        #pragma unroll
        for (int mt = 0; mt < 2; ++mt) {
            int m = mt * 16 + fr;
            #pragma unroll
            for (int rg = 0; rg < 4; ++rg) {
                int jloc = (wave * 2 + jl) * 16 + 4 * g + rg;
                float e = __expf(sacc[jl][mt][rg]);
                e = (jloc < jmax) ? e : 0.f;
                int c = jloc >> 3;
                int pp = (c & 8) | ((c + (m & 7)) & 7);
                Pt[m * 136 + pp * 8 + (jloc & 7)] = f2bf(e);
            }
        }
    }
    __syncthreads();

    if (t < M_) {
        float s = 0.f;
        #pragma unroll
        for (int cc = 0; cc < 16; ++cc) {
            bf16x8 pv = *(const bf16x8*)&Pt[t * 136 + cc * 8];
            #pragma unroll
            for (int e = 0; e < 8; ++e) s += (float)pv[e];
        }
        pden[((size_t)bh * NCH2_ + ch) * M_ + t] = s;
    }

    f32x4 oacc[2] = {};
    int d = wave * 16 + fr;
    int cch = d >> 3, drem = d & 7;
    #pragma unroll
    for (int ks = 0; ks < 4; ++ks) {
        ushort bw[8];
        #pragma unroll
        for (int e = 0; e < 8; ++e) {
            int j = ks * 32 + g * 8 + e;
            int pp = (cch + (j & 7)) & 7;
            bw[e] = Vs[j * 64 + pp * 8 + drem];
        }
        bf16x8 bv = *(const bf16x8*)bw;
        #pragma unroll
        for (int mt = 0; mt < 2; ++mt) {
            int m = mt * 16 + fr;
            int c = ks * 4 + g;
            int pp = (c & 8) | ((c + (m & 7)) & 7);
            bf16x8 ap = *(const bf16x8*)&Pt[m * 136 + pp * 8];
            oacc[mt] = __builtin_amdgcn_mfma_f32_16x16x32_bf16(ap, bv, oacc[mt], 0, 0, 0);
        }
    }
    #pragma unroll
    for (int mt = 0; mt < 2; ++mt) {
        #pragma unroll
        for (int rg = 0; rg < 4; ++rg) {
            int m = mt * 16 + 4 * g + rg;
            if (m < M_)
                pacc[(((size_t)bh * NCH2_ + ch) * M_ + m) * DH_ + d] = oacc[mt][rg];
        }
    }
}

// ---------------- reduce partials -> kv, then akv = ainv @ kv ----------------
__global__ __launch_bounds__(256) void akv_kernel(const float* __restrict__ ainv,
        const float* __restrict__ pacc, const float* __restrict__ pden,
        float* __restrict__ akv) {
    int bh = blockIdx.x;
    __shared__ float kvs[M_ * DH_];
    __shared__ float inv_s[M_ * M_];
    __shared__ float den[M_];
    int t = threadIdx.x;
    for (int i = t; i < M_ * M_; i += 256) inv_s[i] = ainv[(size_t)bh * 400 + i];
    if (t < M_) {
        float s = 0.f;
        for (int c = 0; c < NCH2_; ++c) s += pden[((size_t)bh * NCH2_ + c) * M_ + t];
        den[t] = s;
    }
    __syncthreads();
    for (int idx = t; idx < M_ * DH_; idx += 256) {
        int m = idx >> 6;
        float s = 0.f;
        #pragma unroll 4
        for (int c = 0; c < NCH2_; ++c) s += pacc[((size_t)bh * NCH2_ + c) * M_ * DH_ + idx];
        kvs[idx] = s / den[m];
    }
    __syncthreads();
    for (int idx = t; idx < M_ * DH_; idx += 256) {
        int m = idx >> 6, d = idx & 63;
        float s = 0.f;
        #pragma unroll
        for (int mm = 0; mm < M_; ++mm) s += inv_s[m * M_ + mm] * kvs[mm * DH_ + d];
        akv[(size_t)bh * M_ * DH_ + idx] = s;
    }
}

// ---------------- fused conv + attention epilogue, 64 rows per block ----------------
__global__ __launch_bounds__(256) void out_attn_kernel(const ushort* __restrict__ q,
        const ushort* __restrict__ v, const float* __restrict__ kland,
        const float* __restrict__ akv, const float* __restrict__ resk,
        ushort* __restrict__ att_out) {
    int bh = blockIdx.y;
    int b = bh / H_, h = bh - b * H_;
    int r0 = blockIdx.x * 64;
    __shared__ ushort Vs[96 * 64];      // 12 KB, rows r0-16 .. r0+79, zero-padded
    __shared__ float  Cs[64 * 65];      // 16.6 KB conv result, padded stride
    __shared__ float  klf[M_ * DH_];    // 5 KB
    __shared__ float  akvs[M_ * DH_];   // 5 KB
    int t = threadIdx.x;

    const ushort* vbase = v + (size_t)bh * N_ * DH_;
    #pragma unroll
    for (int i = 0; i < 3; ++i) {
        int c2 = t + i * 256;              // 768 16B-chunks total
        int row = c2 >> 3, ch = c2 & 7;
        int gr = r0 - 16 + row;
        uint4 val = make_uint4(0u, 0u, 0u, 0u);
        if (gr >= 0 && gr < N_) val = *(const uint4*)(vbase + (size_t)gr * DH_ + ch * 8);
        *(uint4*)&Vs[row * 64 + ch * 8] = val;
    }
    for (int i = t; i < M_ * DH_; i += 256) {
        klf[i]  = kland[(size_t)bh * M_ * DH_ + i];
        akvs[i] = akv[(size_t)bh * M_ * DH_ + i];
    }
    // taps: uniform global loads -> SGPRs
    float kr[KW_];
    #pragma unroll
    for (int tt = 0; tt < KW_; ++tt) kr[tt] = resk[h * KW_ + tt];
    __syncthreads();

    {   // conv phase
        int g = t >> 6, d = t & 63;
        float vv[48];
        #pragma unroll
        for (int j = 0; j < 48; ++j) vv[j] = bf2f(Vs[(g * 16 + j) * 64 + d]);
        #pragma unroll
        for (int rr = 0; rr < 16; ++rr) {
            float s = 0.f;
            #pragma unroll
            for (int tt = 0; tt < KW_; ++tt) s += kr[tt] * vv[rr + tt];
            Cs[(g * 16 + rr) * 65 + d] = s;
        }
    }
    __syncthreads();

    // attention phase
    int rr = t >> 2, quad = t & 3;
    int r = r0 + rr;
    bool valid = r < N_;
    int rc = valid ? r : N_ - 1;

    float qf[16];
    const uint4* qp = (const uint4*)(q + ((size_t)bh * N_ + rc) * DH_ + quad * 16);
    #pragma unroll
    for (int c = 0; c < 2; ++c) {
        uint4 u = qp[c];
        qf[c*8+0] = bf2f((ushort)(u.x & 0xFFFF)); qf[c*8+1] = bf2f((ushort)(u.x >> 16));
        qf[c*8+2] = bf2f((ushort)(u.y & 0xFFFF)); qf[c*8+3] = bf2f((ushort)(u.y >> 16));
        qf[c*8+4] = bf2f((ushort)(u.z & 0xFFFF)); qf[c*8+5] = bf2f((ushort)(u.z >> 16));
        qf[c*8+6] = bf2f((ushort)(u.w & 0xFFFF)); qf[c*8+7] = bf2f((ushort)(u.w >> 16));
    }

    float p[M_];
    #pragma unroll
    for (int m = 0; m < M_; ++m) {
        const float* kl = &klf[m * DH_ + quad * 16];
        float s = 0.f;
        #pragma unroll
        for (int dd = 0; dd < 16; ++dd) s += qf[dd] * kl[dd];
        s += __shfl_xor(s, 1);       // combine the 4 quads of this row
        s += __shfl_xor(s, 2);
        p[m] = s;
    }
    float mx = -1e30f;
    #pragma unroll
    for (int m = 0; m < M_; ++m) mx = fmaxf(mx, p[m]);
    float ssum = 0.f;
    #pragma unroll
    for (int m = 0; m < M_; ++m) { p[m] = __expf(p[m] - mx); ssum += p[m]; }
    float rinv = 1.0f / ssum;
    #pragma unroll
    for (int m = 0; m < M_; ++m) p[m] *= rinv;

    float out[16];
    #pragma unroll
    for (int dd = 0; dd < 16; ++dd) out[dd] = Cs[rr * 65 + quad * 16 + dd];
    #pragma unroll
    for (int m = 0; m < M_; ++m) {
        float w = p[m];
        const float* av = &akvs[m * DH_ + quad * 16];
        #pragma unroll
        for (int dd = 0; dd < 16; ++dd) out[dd] += w * av[dd];
    }

    if (valid) {
        ushort* op = att_out + ((size_t)(b * N_ + r)) * INNER_ + h * DH_ + quad * 16;
        #pragma unroll
        for (int c = 0; c < 2; ++c) {
            uint4 w4;
            w4.x = (unsigned)f2bf(out[c*8+0]) | ((unsigned)f2bf(out[c*8+1]) << 16);
            w4.y = (unsigned)f2bf(out[c*8+2]) | ((unsigned)f2bf(out[c*8+3]) << 16);
            w4.z = (unsigned)f2bf(out[c*8+4]) | ((unsigned)f2bf(out[c*8+5]) << 16);
            w4.w = (unsigned)f2bf(out[c*8+6]) | ((unsigned)f2bf(out[c*8+7]) << 16);
            ((uint4*)op)[c] = w4;
        }
    }
}

// ---------------- launcher ----------------
extern "C" void kernel_launch(void* const* d_in, const int* in_sizes, int n_in,
                              void* d_out, int out_size, void* d_ws, size_t ws_size,
                              hipStream_t stream) {
    const float* x      = (const float*)d_in[0];
    const float* norm_w = (const float*)d_in[1];
    const float* norm_b = (const float*)d_in[2];
    const float* w_qkv  = (const float*)d_in[3];
    const float* w_out  = (const float*)d_in[4];
    const float* b_out  = (const float*)d_in[5];
    const float* res_k  = (const float*)d_in[6];

    char* wsp = (char*)d_ws;
    size_t off = 0;
    auto alloc = [&](size_t bytes) -> void* {
        void* p = wsp + off;
        off = (off + bytes + 255) & ~(size_t)255;
        return p;
    };
    ushort* xn    = (ushort*)alloc((size_t)ROWS_ * D_ * 2);          // 98.3 MB (reused as att_out)
    ushort* qb    = (ushort*)alloc((size_t)B_ * H_ * N_ * DH_ * 2);  // 73.7 MB
    ushort* kb    = (ushort*)alloc((size_t)B_ * H_ * N_ * DH_ * 2);
    ushort* vb    = (ushort*)alloc((size_t)B_ * H_ * N_ * DH_ * 2);
    ushort* wqkvT = (ushort*)alloc((size_t)3 * INNER_ * D_ * 2);
    ushort* woutT = (ushort*)alloc((size_t)D_ * INNER_ * 2);
    float*  qland = (float*)alloc((size_t)B_ * H_ * M_ * DH_ * 4);
    float*  kland = (float*)alloc((size_t)B_ * H_ * M_ * DH_ * 4);
    float*  attn2 = (float*)alloc((size_t)B_ * H_ * 400 * 4);
    float*  ainv  = (float*)alloc((size_t)B_ * H_ * 400 * 4);
    float*  pacc  = (float*)alloc((size_t)B_ * H_ * NCH2_ * M_ * DH_ * 4);  // 23.1 MB
    float*  pden  = (float*)alloc((size_t)B_ * H_ * NCH2_ * M_ * 4);
    float*  akvb  = (float*)alloc((size_t)B_ * H_ * M_ * DH_ * 4);
    unsigned* gmx = (unsigned*)alloc(256);
    ushort* att_out = xn;   // xn dead after QKV GEMM

    hipMemsetAsync(gmx, 0, 8, stream);

    int tn = 3 * INNER_ * D_;
    transpose_cast_kernel<<<(tn + 255) / 256, 256, 0, stream>>>(w_qkv, wqkvT, D_, 3 * INNER_);
    tn = D_ * INNER_;
    transpose_cast_kernel<<<(tn + 255) / 256, 256, 0, stream>>>(w_out, woutT, INNER_, D_);

    ln_kernel<<<ROWS_ / 4, 256, 0, stream>>>(x, norm_w, norm_b, xn);

    gemm_kernel<D_, 9, 0><<<(ROWS_ / 128) * 9, 256, 0, stream>>>(
        xn, wqkvT, qb, kb, vb, nullptr, nullptr, nullptr);

    landmark_kernel<<<dim3(B_ * H_ * M_, 2), 64, 0, stream>>>(qb, kb, qland, kland);

    attn2_kernel<<<B_ * H_, 512, 0, stream>>>(qland, kland, attn2, gmx);
    pinv_kernel<<<B_ * H_, 512, 0, stream>>>(attn2, gmx, ainv);

    attn3v_mfma_kernel<<<dim3(NCH2_, B_ * H_), 256, 0, stream>>>(qland, kb, vb, pacc, pden);

    akv_kernel<<<B_ * H_, 256, 0, stream>>>(ainv, pacc, pden, akvb);

    out_attn_kernel<<<dim3((N_ + 63) / 64, B_ * H_), 256, 0, stream>>>(
        qb, vb, kland, akvb, res_k, att_out);

    gemm_kernel<INNER_, 4, 1><<<(ROWS_ / 128) * 4, 256, 0, stream>>>(
        att_out, woutT, nullptr, nullptr, nullptr, (float*)d_out, x, b_out);
}

// Round 15
// 590.755 us; speedup vs baseline: 1.0684x; 1.0305x over previous
//
#include <hip/hip_runtime.h>

typedef float  f32x4  __attribute__((ext_vector_type(4)));
typedef __bf16 bf16x4 __attribute__((ext_vector_type(4)));
typedef __bf16 bf16x8 __attribute__((ext_vector_type(8)));

#define B_     16
#define N_     6000
#define D_     512
#define H_     6
#define DH_    64
#define INNER_ 384
#define M_     20
#define L_     300
#define KW_    33
#define ROWS_  (B_ * N_)     // 96000
#define SCALE_ 0.125f        // 64^-0.5
#define CH2_   128           // attn3 chunk rows (MFMA version)
#define NCH2_  47            // ceil(6000/128)

__device__ __forceinline__ ushort f2bf(float f) {
    __bf16 h = (__bf16)f;                    // v_cvt (RNE)
    return __builtin_bit_cast(ushort, h);
}
__device__ __forceinline__ float bf2f(ushort h) {
    return __uint_as_float(((unsigned)h) << 16);
}

// async global->LDS, 16B per lane; LDS dest = wave-uniform base + lane*16
#define GLD(gp, lp) __builtin_amdgcn_global_load_lds( \
    (const __attribute__((address_space(1))) unsigned int*)(gp), \
    (__attribute__((address_space(3))) unsigned int*)(lp), 16, 0, 0)

// ---------------- LayerNorm: wave-per-row, shfl-only, no LDS ----------------
__global__ __launch_bounds__(256) void ln_kernel(const float* __restrict__ x,
        const float* __restrict__ w, const float* __restrict__ b,
        ushort* __restrict__ xn) {
    int row  = blockIdx.x * 4 + (threadIdx.x >> 6);
    int lane = threadIdx.x & 63;
    const float4* xp = (const float4*)(x + (size_t)row * D_);
    float4 v0 = xp[lane];
    float4 v1 = xp[lane + 64];
    float s  = v0.x + v0.y + v0.z + v0.w + v1.x + v1.y + v1.z + v1.w;
    float sq = v0.x*v0.x + v0.y*v0.y + v0.z*v0.z + v0.w*v0.w
             + v1.x*v1.x + v1.y*v1.y + v1.z*v1.z + v1.w*v1.w;
    #pragma unroll
    for (int o = 32; o; o >>= 1) { s += __shfl_xor(s, o); sq += __shfl_xor(sq, o); }
    float mu   = s * (1.0f / D_);
    float var  = sq * (1.0f / D_) - mu * mu;
    float rstd = rsqrtf(var + 1e-5f);
    const float4 wv0 = ((const float4*)w)[lane];
    const float4 wv1 = ((const float4*)w)[lane + 64];
    const float4 bv0 = ((const float4*)b)[lane];
    const float4 bv1 = ((const float4*)b)[lane + 64];
    ushort4 o0, o1;
    o0.x = f2bf((v0.x - mu) * rstd * wv0.x + bv0.x);
    o0.y = f2bf((v0.y - mu) * rstd * wv0.y + bv0.y);
    o0.z = f2bf((v0.z - mu) * rstd * wv0.z + bv0.z);
    o0.w = f2bf((v0.w - mu) * rstd * wv0.w + bv0.w);
    o1.x = f2bf((v1.x - mu) * rstd * wv1.x + bv1.x);
    o1.y = f2bf((v1.y - mu) * rstd * wv1.y + bv1.y);
    o1.z = f2bf((v1.z - mu) * rstd * wv1.z + bv1.z);
    o1.w = f2bf((v1.w - mu) * rstd * wv1.w + bv1.w);
    ((ushort4*)(xn + (size_t)row * D_))[lane]      = o0;
    ((ushort4*)(xn + (size_t)row * D_))[lane + 64] = o1;
}

// ---------------- transpose + cast f32 W[R][C] -> bf16 WT[C][R] ----------------
__global__ void transpose_cast_kernel(const float* __restrict__ W, ushort* __restrict__ WT,
                                      int R, int C) {
    int idx = blockIdx.x * blockDim.x + threadIdx.x;
    if (idx >= R * C) return;
    int r = idx / C, c = idx - r * C;
    WT[(size_t)c * R + r] = f2bf(W[idx]);
}

// ---------------- bf16 MFMA GEMM (R7 verified structure, 128x128, BK=32) ----------------
// Single-buffer global_load_lds staging, 16B-chunk rotation swizzle
// (bank-conflict-free, measured 0), bijective XCD chunking, n-fastest 1D grid.
// Structure ceiling verified: dbuf (R8), 256-tile (R10), triple-buffer counted
// vmcnt (R12), BK=64 (R13) all neutral-or-worse. Do not re-attempt.
template<int KDIM, int NT, int EPI>
__global__ __launch_bounds__(256) void gemm_kernel(
        const ushort* __restrict__ A, const ushort* __restrict__ BT,
        ushort* __restrict__ qo, ushort* __restrict__ ko, ushort* __restrict__ vo,
        float* __restrict__ outp, const float* __restrict__ xres, const float* __restrict__ bout) {
    __shared__ __align__(16) ushort As[128 * 32];
    __shared__ __align__(16) ushort Bs[128 * 32];

    const int nwg = (int)gridDim.x;
    const int orig = (int)blockIdx.x;
    const int qd = nwg >> 3, rm = nwg & 7;
    const int xcd = orig & 7, loc = orig >> 3;
    const int wg = (xcd < rm ? xcd * (qd + 1) : rm * (qd + 1) + (xcd - rm) * qd) + loc;
    const int m0 = (wg / NT) * 128, n0 = (wg % NT) * 128;

    const int tid = threadIdx.x;
    const int lane = tid & 63, wave = tid >> 6;
    const int wm = (wave >> 1) * 64, wn = (wave & 1) * 64;
    const int fr = lane & 15;

    const int seg0 = wave * 2, seg1 = wave * 2 + 1;
    const int srow0 = seg0 * 16 + (lane >> 2);
    const int srow1 = seg1 * 16 + (lane >> 2);
    const int scol  = ((((lane & 3) - ((lane >> 3) & 3)) & 3) * 8);
    const ushort* Ag0 = A  + (size_t)(m0 + srow0) * KDIM + scol;
    const ushort* Ag1 = A  + (size_t)(m0 + srow1) * KDIM + scol;
    const ushort* Bg0 = BT + (size_t)(n0 + srow0) * KDIM + scol;
    const ushort* Bg1 = BT + (size_t)(n0 + srow1) * KDIM + scol;
    ushort* Al0 = &As[seg0 * 512];
    ushort* Al1 = &As[seg1 * 512];
    ushort* Bl0 = &Bs[seg0 * 512];
    ushort* Bl1 = &Bs[seg1 * 512];

    const int rp = (((lane >> 4) + (fr >> 1)) & 3) * 8;

    f32x4 acc[4][4] = {};

    for (int k0 = 0; k0 < KDIM; k0 += 32) {
        __syncthreads();
        GLD(Ag0 + k0, Al0);
        GLD(Ag1 + k0, Al1);
        GLD(Bg0 + k0, Bl0);
        GLD(Bg1 + k0, Bl1);
        __syncthreads();   // compiler drains vmcnt(0) before barrier
        bf16x8 af[4], bfv[4];
        #pragma unroll
        for (int i = 0; i < 4; ++i) {
            af[i]  = *(const bf16x8*)&As[(wm + i * 16 + fr) * 32 + rp];
            bfv[i] = *(const bf16x8*)&Bs[(wn + i * 16 + fr) * 32 + rp];
        }
        #pragma unroll
        for (int i = 0; i < 4; ++i)
            #pragma unroll
            for (int j = 0; j < 4; ++j)
                acc[i][j] = __builtin_amdgcn_mfma_f32_16x16x32_bf16(af[i], bfv[j], acc[i][j], 0, 0, 0);
    }

    #pragma unroll
    for (int i = 0; i < 4; ++i) {
        #pragma unroll
        for (int j = 0; j < 4; ++j) {
            #pragma unroll
            for (int rg = 0; rg < 4; ++rg) {
                int gr = m0 + wm + i * 16 + ((lane >> 4) << 2) + rg;
                int gc = n0 + wn + j * 16 + (lane & 15);
                float val = acc[i][j][rg];
                if (EPI == 0) {
                    int bb = gr / N_, ii = gr - bb * N_;
                    int part = gc / INNER_, rem = gc - part * INNER_;
                    int h = rem >> 6, d = rem & 63;
                    size_t di = (((size_t)bb * H_ + h) * N_ + ii) * DH_ + d;
                    if (part == 0)      qo[di] = f2bf(val * SCALE_);
                    else if (part == 1) ko[di] = f2bf(val);
                    else                vo[di] = f2bf(val);
                } else {
                    size_t oi = (size_t)gr * D_ + gc;
                    outp[oi] = val + bout[gc] + xres[oi];
                }
            }
        }
    }
}

// ---------------- landmark means over L=300, vectorized ----------------
// 256 threads per (bh, m): thread = (row-group rg = t>>4, col-chunk c4 = (t&15)*4).
// uint2 loads (4 bf16): a wave covers 4 rows x 128B fully coalesced (512B/instr).
// 19 strided iterations; partial sums reduced via stride-65 LDS tile
// (scalar writes bank-clean; read banks rotate (t+r)&31 -> 2 lanes/bank, free).
__global__ __launch_bounds__(256) void landmark_kernel(const ushort* __restrict__ q,
        const ushort* __restrict__ k, float* __restrict__ qland, float* __restrict__ kland) {
    int bhm = blockIdx.x;
    int bh = bhm / M_, m = bhm - bh * M_;
    const ushort* src = (blockIdx.y == 0) ? q : k;
    float* dst = (blockIdx.y == 0) ? qland : kland;
    __shared__ float red[16 * 65];
    int t = threadIdx.x;
    int rg = t >> 4, c4 = (t & 15) * 4;
    const ushort* base = src + ((size_t)bh * N_ + m * L_) * DH_ + c4;
    float s0 = 0.f, s1 = 0.f, s2 = 0.f, s3 = 0.f;
    for (int j = rg; j < L_; j += 16) {
        uint2 u = *(const uint2*)(base + (size_t)j * DH_);
        s0 += bf2f((ushort)(u.x & 0xFFFF));
        s1 += bf2f((ushort)(u.x >> 16));
        s2 += bf2f((ushort)(u.y & 0xFFFF));
        s3 += bf2f((ushort)(u.y >> 16));
    }
    red[rg * 65 + c4 + 0] = s0;
    red[rg * 65 + c4 + 1] = s1;
    red[rg * 65 + c4 + 2] = s2;
    red[rg * 65 + c4 + 3] = s3;
    __syncthreads();
    if (t < DH_) {
        float s = 0.f;
        #pragma unroll
        for (int r = 0; r < 16; ++r) s += red[r * 65 + t];
        dst[((size_t)bh * M_ + m) * DH_ + t] = s * (1.0f / L_);
    }
}

// ---------------- attn2 = softmax(q_land k_land^T) + global max row/col sums ----------------
__global__ __launch_bounds__(512) void attn2_kernel(const float* __restrict__ qland,
        const float* __restrict__ kland, float* __restrict__ attn2, unsigned* __restrict__ gmax) {
    int bh = blockIdx.x;
    __shared__ float sim[M_ * M_];
    int t = threadIdx.x;
    if (t < M_ * M_) {
        int i = t / M_, j = t - (t / M_) * M_;
        const float* qp = qland + ((size_t)bh * M_ + i) * DH_;
        const float* kp = kland + ((size_t)bh * M_ + j) * DH_;
        float s = 0.f;
        for (int d = 0; d < DH_; ++d) s += qp[d] * kp[d];
        sim[t] = s;
    }
    __syncthreads();
    if (t < M_) {
        float mx = -1e30f;
        for (int j = 0; j < M_; ++j) mx = fmaxf(mx, sim[t * M_ + j]);
        float s = 0.f;
        for (int j = 0; j < M_; ++j) { float e = __expf(sim[t * M_ + j] - mx); sim[t * M_ + j] = e; s += e; }
        float inv = 1.0f / s;
        for (int j = 0; j < M_; ++j) sim[t * M_ + j] *= inv;
    }
    __syncthreads();
    if (t < M_ * M_) attn2[(size_t)bh * 400 + t] = sim[t];
    if (t < M_) {
        float cs = 0.f, rs = 0.f;
        for (int i = 0; i < M_; ++i) { cs += sim[i * M_ + t]; rs += sim[t * M_ + i]; }
        atomicMax(&gmax[1], __float_as_uint(cs));
        atomicMax(&gmax[0], __float_as_uint(rs));
    }
}

// ---------------- Newton-Schulz pinv, 6 iters, 20x20 per (b,h) ----------------
__global__ __launch_bounds__(512) void pinv_kernel(const float* __restrict__ attn2,
        const unsigned* __restrict__ gmax, float* __restrict__ ainv) {
    int bh = blockIdx.x;
    __shared__ float buf[5 * 400];
    float* pa = buf; float* pz = buf + 400; float* m1 = buf + 800; float* m2 = buf + 1200; float* m3 = buf + 1600;
    int t = threadIdx.x;
    float rden = 1.0f / (__uint_as_float(gmax[0]) * __uint_as_float(gmax[1]));
    int i = t / M_, j = t - (t / M_) * M_;
    if (t < 400) {
        pa[t] = attn2[(size_t)bh * 400 + t];
        pz[t] = attn2[(size_t)bh * 400 + j * M_ + i] * rden;   // a^T / denom
    }
    for (int it = 0; it < 6; ++it) {
        __syncthreads();
        if (t < 400) { float s = 0; for (int kk = 0; kk < M_; ++kk) s += pa[i * M_ + kk] * pz[kk * M_ + j]; m1[t] = s; }
        __syncthreads();
        if (t < 400) { float s = 0; for (int kk = 0; kk < M_; ++kk) s += m1[i * M_ + kk] * m1[kk * M_ + j]; m2[t] = 7.0f * m1[t] - s; }
        __syncthreads();
        if (t < 400) { float s = 0; for (int kk = 0; kk < M_; ++kk) s += m1[i * M_ + kk] * m2[kk * M_ + j]; m3[t] = 15.0f * m1[t] - s; }
        __syncthreads();
        if (t < 400) { float s = 0; for (int kk = 0; kk < M_; ++kk) s += pz[i * M_ + kk] * m3[kk * M_ + j]; m2[t] = 0.25f * (13.0f * pz[t] - s); }
        __syncthreads();
        float* tmp = pz; pz = m2; m2 = tmp;
    }
    if (t < 400) ainv[(size_t)bh * 400 + t] = pz[t];
}

// ---------------- attn3@v chunk partials via MFMA (R11 verified) ----------------
__global__ __launch_bounds__(256) void attn3v_mfma_kernel(
        const float* __restrict__ qland, const ushort* __restrict__ k,
        const ushort* __restrict__ v, float* __restrict__ pacc, float* __restrict__ pden) {
    int ch = blockIdx.x, bh = blockIdx.y;
    __shared__ __align__(16) ushort Ks[CH2_ * 64];    // 16 KB, chunk-rotated rows
    __shared__ __align__(16) ushort Vs[CH2_ * 64];    // 16 KB
    __shared__ __align__(16) ushort qlb[32 * 64];     // 4 KB, rows >=20 zero
    __shared__ __align__(16) ushort Pt[32 * 136];     // 8.5 KB, rotated, 8-pad
    int t = threadIdx.x;
    int lane = t & 63, wave = t >> 6;
    int j0 = ch * CH2_;
    int jmax = N_ - j0; if (jmax > CH2_) jmax = CH2_;

    const ushort* kbase = k + ((size_t)bh * N_ + j0) * DH_;
    const ushort* vbase = v + ((size_t)bh * N_ + j0) * DH_;
    #pragma unroll
    for (int i = 0; i < 4; ++i) {
        int pdx = (wave * 4 + i) * 64 + lane;
        int row = pdx >> 3, pp = pdx & 7;
        int c = (pp - (row & 7)) & 7;
        int rowc = row < jmax ? row : jmax - 1;
        GLD(kbase + (size_t)rowc * DH_ + c * 8, &Ks[pdx * 8]);
        GLD(vbase + (size_t)rowc * DH_ + c * 8, &Vs[pdx * 8]);
    }
    {
        int row = t >> 3, pp = t & 7;
        int c = (pp - (row & 7)) & 7;
        ushort w8[8];
        if (row < M_) {
            const float* qp = qland + ((size_t)bh * M_ + row) * DH_ + c * 8;
            #pragma unroll
            for (int e = 0; e < 8; ++e) w8[e] = f2bf(qp[e]);
        } else {
            #pragma unroll
            for (int e = 0; e < 8; ++e) w8[e] = 0;
        }
        *(uint4*)&qlb[t * 8] = *(const uint4*)w8;
    }
    __syncthreads();

    int fr = lane & 15, g = lane >> 4;

    f32x4 sacc[2][2] = {};
    #pragma unroll
    for (int ks = 0; ks < 2; ++ks) {
        bf16x8 bq[2];
        #pragma unroll
        for (int mt = 0; mt < 2; ++mt) {
            int m = mt * 16 + fr;
            int c = ks * 4 + g;
            int pp = (c + (m & 7)) & 7;
            bq[mt] = *(const bf16x8*)&qlb[m * 64 + pp * 8];
        }
        #pragma unroll
        for (int jl = 0; jl < 2; ++jl) {
            int row = (wave * 2 + jl) * 16 + fr;
            int c = ks * 4 + g;
            int pp = (c + (row & 7)) & 7;
            bf16x8 ak = *(const bf16x8*)&Ks[row * 64 + pp * 8];
            #pragma unroll
            for (int mt = 0; mt < 2; ++mt)
                sacc[jl][mt] = __builtin_amdgcn_mfma_f32_16x16x32_bf16(ak, bq[mt], sacc[jl][mt], 0, 0, 0);
        }
    }
    #pragma unroll
    for (int jl = 0; jl < 2; ++jl) {
        #pragma unroll
        for (int mt = 0; mt < 2; ++mt) {
            int m = mt * 16 + fr;
            #pragma unroll
            for (int rg = 0; rg < 4; ++rg) {
                int jloc = (wave * 2 + jl) * 16 + 4 * g + rg;
                float e = __expf(sacc[jl][mt][rg]);
                e = (jloc < jmax) ? e : 0.f;
                int c = jloc >> 3;
                int pp = (c & 8) | ((c + (m & 7)) & 7);
                Pt[m * 136 + pp * 8 + (jloc & 7)] = f2bf(e);
            }
        }
    }
    __syncthreads();

    if (t < M_) {
        float s = 0.f;
        #pragma unroll
        for (int cc = 0; cc < 16; ++cc) {
            bf16x8 pv = *(const bf16x8*)&Pt[t * 136 + cc * 8];
            #pragma unroll
            for (int e = 0; e < 8; ++e) s += (float)pv[e];
        }
        pden[((size_t)bh * NCH2_ + ch) * M_ + t] = s;
    }

    f32x4 oacc[2] = {};
    int d = wave * 16 + fr;
    int cch = d >> 3, drem = d & 7;
    #pragma unroll
    for (int ks = 0; ks < 4; ++ks) {
        ushort bw[8];
        #pragma unroll
        for (int e = 0; e < 8; ++e) {
            int j = ks * 32 + g * 8 + e;
            int pp = (cch + (j & 7)) & 7;
            bw[e] = Vs[j * 64 + pp * 8 + drem];
        }
        bf16x8 bv = *(const bf16x8*)bw;
        #pragma unroll
        for (int mt = 0; mt < 2; ++mt) {
            int m = mt * 16 + fr;
            int c = ks * 4 + g;
            int pp = (c & 8) | ((c + (m & 7)) & 7);
            bf16x8 ap = *(const bf16x8*)&Pt[m * 136 + pp * 8];
            oacc[mt] = __builtin_amdgcn_mfma_f32_16x16x32_bf16(ap, bv, oacc[mt], 0, 0, 0);
        }
    }
    #pragma unroll
    for (int mt = 0; mt < 2; ++mt) {
        #pragma unroll
        for (int rg = 0; rg < 4; ++rg) {
            int m = mt * 16 + 4 * g + rg;
            if (m < M_)
                pacc[(((size_t)bh * NCH2_ + ch) * M_ + m) * DH_ + d] = oacc[mt][rg];
        }
    }
}

// ---------------- reduce partials -> kv, then akv = ainv @ kv ----------------
__global__ __launch_bounds__(256) void akv_kernel(const float* __restrict__ ainv,
        const float* __restrict__ pacc, const float* __restrict__ pden,
        float* __restrict__ akv) {
    int bh = blockIdx.x;
    __shared__ float kvs[M_ * DH_];
    __shared__ float inv_s[M_ * M_];
    __shared__ float den[M_];
    int t = threadIdx.x;
    for (int i = t; i < M_ * M_; i += 256) inv_s[i] = ainv[(size_t)bh * 400 + i];
    if (t < M_) {
        float s = 0.f;
        for (int c = 0; c < NCH2_; ++c) s += pden[((size_t)bh * NCH2_ + c) * M_ + t];
        den[t] = s;
    }
    __syncthreads();
    for (int idx = t; idx < M_ * DH_; idx += 256) {
        int m = idx >> 6;
        float s = 0.f;
        #pragma unroll 4
        for (int c = 0; c < NCH2_; ++c) s += pacc[((size_t)bh * NCH2_ + c) * M_ * DH_ + idx];
        kvs[idx] = s / den[m];
    }
    __syncthreads();
    for (int idx = t; idx < M_ * DH_; idx += 256) {
        int m = idx >> 6, d = idx & 63;
        float s = 0.f;
        #pragma unroll
        for (int mm = 0; mm < M_; ++mm) s += inv_s[m * M_ + mm] * kvs[mm * DH_ + d];
        akv[(size_t)bh * M_ * DH_ + idx] = s;
    }
}

// ---------------- fused conv + attention epilogue, 64 rows per block ----------------
__global__ __launch_bounds__(256) void out_attn_kernel(const ushort* __restrict__ q,
        const ushort* __restrict__ v, const float* __restrict__ kland,
        const float* __restrict__ akv, const float* __restrict__ resk,
        ushort* __restrict__ att_out) {
    int bh = blockIdx.y;
    int b = bh / H_, h = bh - b * H_;
    int r0 = blockIdx.x * 64;
    __shared__ ushort Vs[96 * 64];      // 12 KB, rows r0-16 .. r0+79, zero-padded
    __shared__ float  Cs[64 * 65];      // 16.6 KB conv result, padded stride
    __shared__ float  klf[M_ * DH_];    // 5 KB
    __shared__ float  akvs[M_ * DH_];   // 5 KB
    int t = threadIdx.x;

    const ushort* vbase = v + (size_t)bh * N_ * DH_;
    #pragma unroll
    for (int i = 0; i < 3; ++i) {
        int c2 = t + i * 256;              // 768 16B-chunks total
        int row = c2 >> 3, ch = c2 & 7;
        int gr = r0 - 16 + row;
        uint4 val = make_uint4(0u, 0u, 0u, 0u);
        if (gr >= 0 && gr < N_) val = *(const uint4*)(vbase + (size_t)gr * DH_ + ch * 8);
        *(uint4*)&Vs[row * 64 + ch * 8] = val;
    }
    for (int i = t; i < M_ * DH_; i += 256) {
        klf[i]  = kland[(size_t)bh * M_ * DH_ + i];
        akvs[i] = akv[(size_t)bh * M_ * DH_ + i];
    }
    // taps: uniform global loads -> SGPRs
    float kr[KW_];
    #pragma unroll
    for (int tt = 0; tt < KW_; ++tt) kr[tt] = resk[h * KW_ + tt];
    __syncthreads();

    {   // conv phase
        int g = t >> 6, d = t & 63;
        float vv[48];
        #pragma unroll
        for (int j = 0; j < 48; ++j) vv[j] = bf2f(Vs[(g * 16 + j) * 64 + d]);
        #pragma unroll
        for (int rr = 0; rr < 16; ++rr) {
            float s = 0.f;
            #pragma unroll
            for (int tt = 0; tt < KW_; ++tt) s += kr[tt] * vv[rr + tt];
            Cs[(g * 16 + rr) * 65 + d] = s;
        }
    }
    __syncthreads();

    // attention phase
    int rr = t >> 2, quad = t & 3;
    int r = r0 + rr;
    bool valid = r < N_;
    int rc = valid ? r : N_ - 1;

    float qf[16];
    const uint4* qp = (const uint4*)(q + ((size_t)bh * N_ + rc) * DH_ + quad * 16);
    #pragma unroll
    for (int c = 0; c < 2; ++c) {
        uint4 u = qp[c];
        qf[c*8+0] = bf2f((ushort)(u.x & 0xFFFF)); qf[c*8+1] = bf2f((ushort)(u.x >> 16));
        qf[c*8+2] = bf2f((ushort)(u.y & 0xFFFF)); qf[c*8+3] = bf2f((ushort)(u.y >> 16));
        qf[c*8+4] = bf2f((ushort)(u.z & 0xFFFF)); qf[c*8+5] = bf2f((ushort)(u.z >> 16));
        qf[c*8+6] = bf2f((ushort)(u.w & 0xFFFF)); qf[c*8+7] = bf2f((ushort)(u.w >> 16));
    }

    float p[M_];
    #pragma unroll
    for (int m = 0; m < M_; ++m) {
        const float* kl = &klf[m * DH_ + quad * 16];
        float s = 0.f;
        #pragma unroll
        for (int dd = 0; dd < 16; ++dd) s += qf[dd] * kl[dd];
        s += __shfl_xor(s, 1);       // combine the 4 quads of this row
        s += __shfl_xor(s, 2);
        p[m] = s;
    }
    float mx = -1e30f;
    #pragma unroll
    for (int m = 0; m < M_; ++m) mx = fmaxf(mx, p[m]);
    float ssum = 0.f;
    #pragma unroll
    for (int m = 0; m < M_; ++m) { p[m] = __expf(p[m] - mx); ssum += p[m]; }
    float rinv = 1.0f / ssum;
    #pragma unroll
    for (int m = 0; m < M_; ++m) p[m] *= rinv;

    float out[16];
    #pragma unroll
    for (int dd = 0; dd < 16; ++dd) out[dd] = Cs[rr * 65 + quad * 16 + dd];
    #pragma unroll
    for (int m = 0; m < M_; ++m) {
        float w = p[m];
        const float* av = &akvs[m * DH_ + quad * 16];
        #pragma unroll
        for (int dd = 0; dd < 16; ++dd) out[dd] += w * av[dd];
    }

    if (valid) {
        ushort* op = att_out + ((size_t)(b * N_ + r)) * INNER_ + h * DH_ + quad * 16;
        #pragma unroll
        for (int c = 0; c < 2; ++c) {
            uint4 w4;
            w4.x = (unsigned)f2bf(out[c*8+0]) | ((unsigned)f2bf(out[c*8+1]) << 16);
            w4.y = (unsigned)f2bf(out[c*8+2]) | ((unsigned)f2bf(out[c*8+3]) << 16);
            w4.z = (unsigned)f2bf(out[c*8+4]) | ((unsigned)f2bf(out[c*8+5]) << 16);
            w4.w = (unsigned)f2bf(out[c*8+6]) | ((unsigned)f2bf(out[c*8+7]) << 16);
            ((uint4*)op)[c] = w4;
        }
    }
}

// ---------------- launcher ----------------
extern "C" void kernel_launch(void* const* d_in, const int* in_sizes, int n_in,
                              void* d_out, int out_size, void* d_ws, size_t ws_size,
                              hipStream_t stream) {
    const float* x      = (const float*)d_in[0];
    const float* norm_w = (const float*)d_in[1];
    const float* norm_b = (const float*)d_in[2];
    const float* w_qkv  = (const float*)d_in[3];
    const float* w_out  = (const float*)d_in[4];
    const float* b_out  = (const float*)d_in[5];
    const float* res_k  = (const float*)d_in[6];

    char* wsp = (char*)d_ws;
    size_t off = 0;
    auto alloc = [&](size_t bytes) -> void* {
        void* p = wsp + off;
        off = (off + bytes + 255) & ~(size_t)255;
        return p;
    };
    ushort* xn    = (ushort*)alloc((size_t)ROWS_ * D_ * 2);          // 98.3 MB (reused as att_out)
    ushort* qb    = (ushort*)alloc((size_t)B_ * H_ * N_ * DH_ * 2);  // 73.7 MB
    ushort* kb    = (ushort*)alloc((size_t)B_ * H_ * N_ * DH_ * 2);
    ushort* vb    = (ushort*)alloc((size_t)B_ * H_ * N_ * DH_ * 2);
    ushort* wqkvT = (ushort*)alloc((size_t)3 * INNER_ * D_ * 2);
    ushort* woutT = (ushort*)alloc((size_t)D_ * INNER_ * 2);
    float*  qland = (float*)alloc((size_t)B_ * H_ * M_ * DH_ * 4);
    float*  kland = (float*)alloc((size_t)B_ * H_ * M_ * DH_ * 4);
    float*  attn2 = (float*)alloc((size_t)B_ * H_ * 400 * 4);
    float*  ainv  = (float*)alloc((size_t)B_ * H_ * 400 * 4);
    float*  pacc  = (float*)alloc((size_t)B_ * H_ * NCH2_ * M_ * DH_ * 4);  // 23.1 MB
    float*  pden  = (float*)alloc((size_t)B_ * H_ * NCH2_ * M_ * 4);
    float*  akvb  = (float*)alloc((size_t)B_ * H_ * M_ * DH_ * 4);
    unsigned* gmx = (unsigned*)alloc(256);
    ushort* att_out = xn;   // xn dead after QKV GEMM

    hipMemsetAsync(gmx, 0, 8, stream);

    int tn = 3 * INNER_ * D_;
    transpose_cast_kernel<<<(tn + 255) / 256, 256, 0, stream>>>(w_qkv, wqkvT, D_, 3 * INNER_);
    tn = D_ * INNER_;
    transpose_cast_kernel<<<(tn + 255) / 256, 256, 0, stream>>>(w_out, woutT, INNER_, D_);

    ln_kernel<<<ROWS_ / 4, 256, 0, stream>>>(x, norm_w, norm_b, xn);

    gemm_kernel<D_, 9, 0><<<(ROWS_ / 128) * 9, 256, 0, stream>>>(
        xn, wqkvT, qb, kb, vb, nullptr, nullptr, nullptr);

    landmark_kernel<<<dim3(B_ * H_ * M_, 2), 256, 0, stream>>>(qb, kb, qland, kland);

    attn2_kernel<<<B_ * H_, 512, 0, stream>>>(qland, kland, attn2, gmx);
    pinv_kernel<<<B_ * H_, 512, 0, stream>>>(attn2, gmx, ainv);

    attn3v_mfma_kernel<<<dim3(NCH2_, B_ * H_), 256, 0, stream>>>(qland, kb, vb, pacc, pden);

    akv_kernel<<<B_ * H_, 256, 0, stream>>>(ainv, pacc, pden, akvb);

    out_attn_kernel<<<dim3((N_ + 63) / 64, B_ * H_), 256, 0, stream>>>(
        qb, vb, kland, akvb, res_k, att_out);

    gemm_kernel<INNER_, 4, 1><<<(ROWS_ / 128) * 4, 256, 0, stream>>>(
        att_out, woutT, nullptr, nullptr, nullptr, (float*)d_out, x, b_out);
}